// Round 1
// baseline (67.090 us; speedup 1.0000x reference)
//
#include <hip/hip_runtime.h>

// Depthwise conv1d along L, K=25, replicate padding, + scalar bias.
// x: [B=32, L=2048, C=512] f32 -> out same shape.
// out[b,l,c] = sum_k w[k] * x[b, clamp(l+k-12, 0, L-1), c] + bias
//
// Memory-bound (268 MB min traffic -> ~42 us at 6.3 TB/s).
// Each thread: one float4 of channels x 16 consecutive l outputs.
// Streams 40 input rows through registers, fully unrolled static indexing.

constexpr int K      = 25;
constexpr int HALF   = 12;
constexpr int LCHUNK = 16;
constexpr int BB     = 32;
constexpr int LL     = 2048;
constexpr int CC     = 512;
constexpr int C4     = CC / 4;           // 128 float4 per row
constexpr int NCHUNK = LL / LCHUNK;      // 128

__global__ __launch_bounds__(256) void conv1d_dw_kernel(
    const float* __restrict__ x,
    const float* __restrict__ w,
    const float* __restrict__ bias_p,
    float* __restrict__ out)
{
    const int tid   = blockIdx.x * 256 + threadIdx.x;
    const int c4    = tid & (C4 - 1);          // 0..127
    const int rest  = tid >> 7;
    const int chunk = rest & (NCHUNK - 1);     // 0..127
    const int b     = rest >> 7;               // 0..31

    // Kernel weights into registers (static indices -> stays in regs).
    float wr[K];
#pragma unroll
    for (int k = 0; k < K; ++k) wr[k] = w[k];
    const float bias = bias_p[0];

    const int l0 = chunk * LCHUNK;
    const float4* xb = reinterpret_cast<const float4*>(x) + (size_t)b * LL * C4;
    float4*       ob = reinterpret_cast<float4*>(out)
                       + (size_t)b * LL * C4 + (size_t)l0 * C4 + c4;

    float4 acc[LCHUNK];
#pragma unroll
    for (int j = 0; j < LCHUNK; ++j)
        acc[j] = make_float4(bias, bias, bias, bias);

    // Stream LCHUNK + K - 1 = 40 input rows; each contributes to the
    // accumulators whose kernel tap k = r - j lies in [0, K).
#pragma unroll
    for (int r = 0; r < LCHUNK + K - 1; ++r) {
        int l = l0 + r - HALF;
        l = max(0, min(LL - 1, l));            // replicate padding
        const float4 xv = xb[(size_t)l * C4 + c4];
#pragma unroll
        for (int j = 0; j < LCHUNK; ++j) {
            const int k = r - j;               // compile-time per (r,j)
            if (k >= 0 && k < K) {
                const float wk = wr[k];
                acc[j].x += wk * xv.x;
                acc[j].y += wk * xv.y;
                acc[j].z += wk * xv.z;
                acc[j].w += wk * xv.w;
            }
        }
    }

#pragma unroll
    for (int j = 0; j < LCHUNK; ++j)
        ob[(size_t)j * C4] = acc[j];
}

extern "C" void kernel_launch(void* const* d_in, const int* in_sizes, int n_in,
                              void* d_out, int out_size, void* d_ws, size_t ws_size,
                              hipStream_t stream) {
    const float* x  = (const float*)d_in[0];
    const float* w  = (const float*)d_in[1];
    const float* bp = (const float*)d_in[2];
    float* out      = (float*)d_out;

    const int total_threads = BB * NCHUNK * C4;   // 524288
    const int blocks        = total_threads / 256; // 2048
    conv1d_dw_kernel<<<blocks, 256, 0, stream>>>(x, w, bp, out);
}

// Round 3
// 61.853 us; speedup vs baseline: 1.0847x; 1.0847x over previous
//
#include <hip/hip_runtime.h>

// Depthwise conv1d along L, K=25, replicate padding, + scalar bias.
// x: [B=32, L=2048, C=512] f32 -> out same shape.
// out[b,l,c] = sum_k w[k] * x[b, clamp(l+k-12, 0, L-1), c] + bias
//
// R2 = R1 with the nontemporal-store type fixed: use a native clang
// ext_vector_type(4) instead of HIP_vector_type float4 (builtin rejects
// the struct wrapper). Same layout, same codegen intent.
//
// R1 theory: latency-bound fix. LCHUNK 16->8 (acc 64->32 VGPR, target
// <=64 VGPR for the 8-waves/SIMD bracket), nontemporal stores (output
// never re-read; don't evict halo lines from L2), XCD-aware block swizzle.

typedef float f32x4 __attribute__((ext_vector_type(4)));

constexpr int K      = 25;
constexpr int HALF   = 12;
constexpr int LCHUNK = 8;
constexpr int BB     = 32;
constexpr int LL     = 2048;
constexpr int CC     = 512;
constexpr int C4     = CC / 4;            // 128 f32x4 per row
constexpr int NCHUNK = LL / LCHUNK;       // 256
constexpr int NBLK   = BB * NCHUNK * C4 / 256;  // 4096 blocks

__global__ __launch_bounds__(256) void conv1d_dw_kernel(
    const float* __restrict__ x,
    const float* __restrict__ w,
    const float* __restrict__ bias_p,
    float* __restrict__ out)
{
    // XCD-aware swizzle: blocks round-robin XCDs (bid%8); map so each XCD
    // owns a contiguous run of logical block ids (contiguous L-ranges).
    const int bid  = blockIdx.x;
    const int lbid = (bid & 7) * (NBLK >> 3) + (bid >> 3);

    const int tid   = lbid * 256 + threadIdx.x;
    const int c4    = tid & (C4 - 1);          // 0..127
    const int rest  = tid >> 7;
    const int chunk = rest & (NCHUNK - 1);     // 0..255
    const int b     = rest >> 8;               // 0..31

    // w is wave-uniform -> compiler puts these in SGPRs.
    float wr[K];
#pragma unroll
    for (int k = 0; k < K; ++k) wr[k] = w[k];
    const float bias = bias_p[0];

    const int l0 = chunk * LCHUNK;
    const f32x4* xb = reinterpret_cast<const f32x4*>(x) + (size_t)b * LL * C4;
    f32x4*       ob = reinterpret_cast<f32x4*>(out)
                      + (size_t)b * LL * C4 + (size_t)l0 * C4 + c4;

    f32x4 acc[LCHUNK];
#pragma unroll
    for (int j = 0; j < LCHUNK; ++j)
        acc[j] = (f32x4){bias, bias, bias, bias};

    // Stream LCHUNK + K - 1 = 32 input rows through registers.
#pragma unroll
    for (int r = 0; r < LCHUNK + K - 1; ++r) {
        int l = l0 + r - HALF;
        l = max(0, min(LL - 1, l));            // replicate padding
        const f32x4 xv = xb[(size_t)l * C4 + c4];
#pragma unroll
        for (int j = 0; j < LCHUNK; ++j) {
            const int k = r - j;               // compile-time per (r,j)
            if (k >= 0 && k < K) {
                acc[j] += wr[k] * xv;
            }
        }
    }

#pragma unroll
    for (int j = 0; j < LCHUNK; ++j)
        __builtin_nontemporal_store(acc[j], &ob[(size_t)j * C4]);
}

extern "C" void kernel_launch(void* const* d_in, const int* in_sizes, int n_in,
                              void* d_out, int out_size, void* d_ws, size_t ws_size,
                              hipStream_t stream) {
    const float* x  = (const float*)d_in[0];
    const float* w  = (const float*)d_in[1];
    const float* bp = (const float*)d_in[2];
    float* out      = (float*)d_out;

    conv1d_dw_kernel<<<NBLK, 256, 0, stream>>>(x, w, bp, out);
}